// Round 1
// baseline (339.470 us; speedup 1.0000x reference)
//
#include <hip/hip_runtime.h>
#include <hip/hip_bf16.h>

// GQA block: B=2, S=2048, HID=2048, H=32, G=8, D=64, QPG=4.
// bf16 MFMA 16x16x32; fp32 accumulate. m97-style staging:
// global_load_lds width=16 into unpadded LDS with XOR swizzle
// (chunk_phys = chunk_log ^ (row&7); rows of 64 shorts = 8 chunks of 16B).
// Fragment layouts (HW-verified, learn_hip m89/m120):
//   A-frag:  A[m=lane&15][k=quad*8+j]
//   B-frag:  B[k=quad*8+j][n=lane&15]
//   C/D:     col(n)=lane&15, row(m)=quad*4+reg
// Attention: S^T = K Q^T, O^T = V^T P^T (softmax axis on regs+quads).
// No-max softmax (scores ~N(0,0.9), exp2 has 2^30 headroom, shift-invariant).
// l on the MFMA pipe via register ones-fragment. GQA: block's 4 waves = the 4
// heads of one kv-group sharing one K/V LDS tile; each wave owns its head's q rows.
// R7: K/V dbuf (single barrier/tile) + PER-QSET P buffers + phase-split PV.
// R8: occupancy attack — attn was latency-bound (MfmaUtil 33 / VALU 41 /
// Occ 18.5, grid 512 = 2 blk/CU hard cap). Split q-tile: 32 q/wave (2 qsets),
// grid (64,8,2)=1024 blocks, LDS 64->48 KB => 3 blk/CU (12 waves/CU);
// launch_bounds(256,3); s_setprio(1) around QK and PV MFMA clusters (T5).

typedef __attribute__((ext_vector_type(8))) short shortx8;
typedef __attribute__((ext_vector_type(4))) float floatx4;

#define SEQ 2048
#define QSC 0.1803368801111204f   // (1/8) * log2(e), folded into Wq/bq

#if __has_builtin(__builtin_amdgcn_exp2f)
#define EXP2F(x) __builtin_amdgcn_exp2f(x)
#else
#define EXP2F(x) __expf((x) * 0.6931471805599453f)
#endif

__device__ __forceinline__ unsigned short f2bf(float f) {      // RNE
  union { float f; unsigned u; } a; a.f = f;
  unsigned u = a.u;
  u += 0x7fffu + ((u >> 16) & 1u);
  return (unsigned short)(u >> 16);
}
__device__ __forceinline__ unsigned pk2f(float lo, float hi) { // fast round
  union { float f; unsigned u; } a, b; a.f = lo; b.f = hi;
  return ((a.u + 0x8000u) >> 16) | (((b.u + 0x8000u) >> 16) << 16);
}

// async global->LDS, 16B per lane; LDS dst = uniform base + lane*16
__device__ __forceinline__ void gload16(const unsigned short* g, unsigned short* l) {
  __builtin_amdgcn_global_load_lds((const __attribute__((address_space(1))) void*)g,
                                   (__attribute__((address_space(3))) void*)l, 16, 0, 0);
}

// ---------------- prep: cast x, transpose+cast all weights, concat bias ----------
// grid (64,64,6), block (32,8). z: 0=Wq(*QSC) 1=Wk 2=Wv 3=Wo 4=cast-x 5=bias.
__global__ void prep_kernel(const float* __restrict__ x,
                            const float* __restrict__ Wq, const float* __restrict__ Wk,
                            const float* __restrict__ Wv, const float* __restrict__ Wo,
                            const float* __restrict__ bq, const float* __restrict__ bk,
                            const float* __restrict__ bv,
                            unsigned short* __restrict__ WT,
                            unsigned short* __restrict__ WoT,
                            unsigned short* __restrict__ xb,
                            float* __restrict__ bqkv) {
  const int z = blockIdx.z;
  if (z == 4) {                       // cast x -> bf16, 2048 floats per block
    int fb = blockIdx.y * 64 + blockIdx.x;
    int tid = threadIdx.y * 32 + threadIdx.x;
    int i = fb * 2048 + tid * 8;
    float4 v0 = *(const float4*)(x + i);
    float4 v1 = *(const float4*)(x + i + 4);
    ushort4 o0, o1;
    o0.x = f2bf(v0.x); o0.y = f2bf(v0.y); o0.z = f2bf(v0.z); o0.w = f2bf(v0.w);
    o1.x = f2bf(v1.x); o1.y = f2bf(v1.y); o1.z = f2bf(v1.z); o1.w = f2bf(v1.w);
    *(ushort4*)(xb + i) = o0;
    *(ushort4*)(xb + i + 4) = o1;
    return;
  }
  if (z == 5) {                       // concat bias
    int fb = blockIdx.y * 64 + blockIdx.x;
    if (fb >= 12) return;
    int i = fb * 256 + threadIdx.y * 32 + threadIdx.x;
    if (i < 2048) bqkv[i] = bq[i] * QSC;
    else if (i < 2560) bqkv[i] = bk[i - 2048];
    else if (i < 3072) bqkv[i] = bv[i - 2560];
    return;
  }
  const float* W; unsigned short* D; int N; float sc = 1.f;
  if (z == 0)      { W = Wq; D = WT;               N = 2048; sc = QSC; }
  else if (z == 1) { W = Wk; D = WT + 2048 * 2048; N = 512; }
  else if (z == 2) { W = Wv; D = WT + 2560 * 2048; N = 512; }
  else             { W = Wo; D = WoT;              N = 2048; }
  if (blockIdx.x * 32 >= N) return;

  __shared__ float tile[32][33];
  int xx = blockIdx.x * 32 + threadIdx.x;
  int y0 = blockIdx.y * 32;
  for (int i = 0; i < 32; i += 8)
    tile[threadIdx.y + i][threadIdx.x] = W[(size_t)(y0 + threadIdx.y + i) * N + xx];
  __syncthreads();
  int nx = y0 + threadIdx.x;
  int ny = blockIdx.x * 32 + threadIdx.y;
  for (int i = 0; i < 32; i += 8)
    D[(size_t)(ny + i) * 2048 + nx] = f2bf(tile[threadIdx.x][threadIdx.y + i] * sc);
}

// ---------------- bf16 GEMM (m97 structure): C = A @ BT^T + bias ----------------
// 128x128 tile, BK=64, 4 waves (2x2), global_load_lds staging, swizzled LDS.
// MODE 0: fp32 out. MODE 2: QKV split (Q -> Cout bf16, K -> Kbuf, V -> Vt[gb][d][s]).
template <int MODE>
__global__ __launch_bounds__(256) void gemm_bt(const unsigned short* __restrict__ A,
                                               const unsigned short* __restrict__ BT,
                                               const float* __restrict__ bias,
                                               void* __restrict__ Cout,
                                               unsigned short* __restrict__ Kbuf,
                                               unsigned short* __restrict__ Vt,
                                               int M, int N, int K) {
  __shared__ __align__(16) unsigned short As[128 * 64];
  __shared__ __align__(16) unsigned short Bs[128 * 64];
  const int m0 = blockIdx.x * 128, n0 = blockIdx.y * 128;
  const int tid = threadIdx.x;
  const int lane = tid & 63, wave = tid >> 6;
  const int l15 = lane & 15, quad = lane >> 4;
  const int wm = (wave & 1) * 64, wn = (wave >> 1) * 64;

  const int r8 = lane >> 3;
  const int clog = (lane & 7) ^ r8;
  const unsigned short* aSrc = A + (size_t)(m0 + wave * 32 + r8) * K + clog * 8;
  const unsigned short* bSrc = BT + (size_t)(n0 + wave * 32 + r8) * K + clog * 8;
  unsigned short* aDst = &As[wave * 2048];
  unsigned short* bDst = &Bs[wave * 2048];

  const int s = l15 & 7;
  int aoff[4], boff[4];
#pragma unroll
  for (int i = 0; i < 4; i++) aoff[i] = (wm + i * 16 + l15) * 64 + (quad ^ s) * 8;
#pragma unroll
  for (int j = 0; j < 4; j++) boff[j] = (wn + j * 16 + l15) * 64 + (quad ^ s) * 8;

  floatx4 acc[4][4];
#pragma unroll
  for (int i = 0; i < 4; i++)
#pragma unroll
    for (int j = 0; j < 4; j++)
#pragma unroll
      for (int r = 0; r < 4; r++) acc[i][j][r] = 0.f;

  for (int k0 = 0; k0 < K; k0 += 64) {
    __syncthreads();
#pragma unroll
    for (int j = 0; j < 4; j++) {
      gload16(aSrc + (size_t)j * 8 * K + k0, aDst + j * 512);
      gload16(bSrc + (size_t)j * 8 * K + k0, bDst + j * 512);
    }
    __syncthreads();
    {
      shortx8 af[4], bf[4];
#pragma unroll
      for (int i = 0; i < 4; i++) af[i] = *(const shortx8*)&As[aoff[i]];
#pragma unroll
      for (int j = 0; j < 4; j++) bf[j] = *(const shortx8*)&Bs[boff[j]];
#pragma unroll
      for (int i = 0; i < 4; i++)
#pragma unroll
        for (int j = 0; j < 4; j++)
          acc[i][j] = __builtin_amdgcn_mfma_f32_16x16x32_bf16(af[i], bf[j], acc[i][j], 0, 0, 0);
#pragma unroll
      for (int i = 0; i < 4; i++) af[i] = *(const shortx8*)&As[aoff[i] ^ 32];
#pragma unroll
      for (int j = 0; j < 4; j++) bf[j] = *(const shortx8*)&Bs[boff[j] ^ 32];
#pragma unroll
      for (int i = 0; i < 4; i++)
#pragma unroll
        for (int j = 0; j < 4; j++)
          acc[i][j] = __builtin_amdgcn_mfma_f32_16x16x32_bf16(af[i], bf[j], acc[i][j], 0, 0, 0);
    }
  }

#pragma unroll
  for (int i = 0; i < 4; i++) {
#pragma unroll
    for (int j = 0; j < 4; j++) {
      int col = n0 + wn + j * 16 + l15;
      float bv = bias[col];
#pragma unroll
      for (int r = 0; r < 4; r++) {
        int row = m0 + wm + i * 16 + quad * 4 + r;
        float v = acc[i][j][r] + bv;
        if (MODE == 0) {
          ((float*)Cout)[(size_t)row * N + col] = v;
        } else {
          if (col < 2048) {
            ((unsigned short*)Cout)[(size_t)row * 2048 + col] = f2bf(v);
          } else if (col < 2560) {
            Kbuf[(size_t)row * 512 + (col - 2048)] = f2bf(v);
          } else {
            int g = (col - 2560) >> 6, d = (col - 2560) & 63;
            int b = row >> 11, sidx = row & 2047;
            Vt[(size_t)(((g << 1) | b) * 64 + d) * 2048 + sidx] = f2bf(v);
          }
        }
      }
    }
  }
}

// ---------------- flash attention (group-shared K/V, dbuf + per-qset P) ----------
// grid (S/32=64, G=8, B=2); wave w = head g*4+w. Each wave: 32 q rows as 2
// q-sets of 16. K/V dbuf (1 barrier/tile); P per-qset buffers (no WAR).
// LDS 48 KB -> 3 blocks/CU (12 waves/CU); setprio around MFMA clusters.
__global__ __launch_bounds__(256, 3) void attn_kernel(const unsigned short* __restrict__ Qb,
                                                      const unsigned short* __restrict__ Kb,
                                                      const unsigned short* __restrict__ Vt,
                                                      unsigned short* __restrict__ O) {
  const int qt = blockIdx.x, g = blockIdx.y, b = blockIdx.z;
  const int tid = threadIdx.x;
  const int lane = tid & 63, wave = tid >> 6;
  const int h = g * 4 + wave;
  const int l15 = lane & 15, quad = lane >> 4;

  __shared__ __align__(16) unsigned short Ks[2][64 * 64];  // [t][d] swizzled, 2x8 KB
  __shared__ __align__(16) unsigned short Vs[2][64 * 64];  // [d][t] swizzled, 2x8 KB
  __shared__ __align__(16) unsigned short Ps[4 * 2048];    // 4 waves x 2 qsets x 2KB

  // Q fragments for 2 q-sets (32 q rows per wave)
  shortx8 qf[2][2];
  {
    const unsigned short* qp = Qb + (size_t)(b * SEQ + qt * 32 + l15) * 2048 + h * 64 + quad * 8;
#pragma unroll
    for (int a = 0; a < 2; a++) {
      qf[a][0] = *(const shortx8*)(qp + (size_t)a * 16 * 2048);
      qf[a][1] = *(const shortx8*)(qp + (size_t)a * 16 * 2048 + 32);
    }
  }

  // staging: wave stages rows wave*16..+15 of each tile (2 issues of 8 rows)
  const int r8 = lane >> 3;
  const int clog = (lane & 7) ^ r8;
  const unsigned short* kSrc = Kb + ((size_t)b * SEQ + wave * 16 + r8) * 512 + g * 64 + clog * 8;
  const unsigned short* vSrc = Vt + ((size_t)((g * 2 + b) * 64 + wave * 16 + r8)) * 2048 + clog * 8;

  const int s = l15 & 7;
  int foff[4];
#pragma unroll
  for (int i = 0; i < 4; i++) foff[i] = (i * 16 + l15) * 64 + ((quad ^ s) * 8);

  const int pbase = wave * 2048 + l15 * 64;
  int pw[4];
#pragma unroll
  for (int i = 0; i < 4; i++) pw[i] = (((i * 2 + (quad >> 1)) ^ s) * 8) + (quad & 1) * 4;
  int pr[2];
#pragma unroll
  for (int ks = 0; ks < 2; ks++) pr[ks] = ((ks * 4 + quad) ^ s) * 8;

  shortx8 ones;
#pragma unroll
  for (int j = 0; j < 8; j++) ones[j] = (short)0x3F80;     // bf16 1.0

  floatx4 oacc[2][4], lacc[2];
#pragma unroll
  for (int a = 0; a < 2; a++) {
#pragma unroll
    for (int r = 0; r < 4; r++) lacc[a][r] = 0.f;
#pragma unroll
    for (int nd = 0; nd < 4; nd++)
#pragma unroll
      for (int r = 0; r < 4; r++) oacc[a][nd][r] = 0.f;
  }

  // prologue: stage tile 0 into buffer 0
  {
    unsigned short* kD = &Ks[0][wave * 1024];
    unsigned short* vD = &Vs[0][wave * 1024];
    gload16(kSrc, kD);
    gload16(kSrc + (size_t)8 * 512, kD + 512);
    gload16(vSrc, vD);
    gload16(vSrc + (size_t)8 * 2048, vD + 512);
  }
  __syncthreads();

  for (int it = 0; it < SEQ / 64; it++) {
    const int p = it & 1;
    // prefetch next tile into the other buffer (async; drained by the
    // end-of-iter barrier, ~1 tile of compute later)
    if (it < SEQ / 64 - 1) {
      const size_t t1 = (size_t)(it + 1) * 64;
      unsigned short* kD = &Ks[p ^ 1][wave * 1024];
      unsigned short* vD = &Vs[p ^ 1][wave * 1024];
      gload16(kSrc + t1 * 512, kD);
      gload16(kSrc + (t1 + 8) * 512, kD + 512);
      gload16(vSrc + t1, vD);
      gload16(vSrc + (size_t)8 * 2048 + t1, vD + 512);
    }

    // K fragments (reused by both q-sets)
    shortx8 kf[4][2];
#pragma unroll
    for (int i = 0; i < 4; i++) {
      kf[i][0] = *(const shortx8*)&Ks[p][foff[i]];
      kf[i][1] = *(const shortx8*)&Ks[p][foff[i] ^ 32];
    }

    // phase 1: per q-set QK^T -> exp -> P write (per-qset buffers: qset a+1's
    // MFMAs overlap qset a's exp; no LDS WAR between q-sets)
#pragma unroll
    for (int a = 0; a < 2; a++) {
      floatx4 sc[4];
      __builtin_amdgcn_s_setprio(1);
#pragma unroll
      for (int i = 0; i < 4; i++) {
        floatx4 c = {0.f, 0.f, 0.f, 0.f};
        c = __builtin_amdgcn_mfma_f32_16x16x32_bf16(kf[i][0], qf[a][0], c, 0, 0, 0);
        c = __builtin_amdgcn_mfma_f32_16x16x32_bf16(kf[i][1], qf[a][1], c, 0, 0, 0);
        sc[i] = c;
      }
      __builtin_amdgcn_s_setprio(0);
#pragma unroll
      for (int i = 0; i < 4; i++) {
        float p0 = EXP2F(sc[i][0]), p1 = EXP2F(sc[i][1]);
        float p2 = EXP2F(sc[i][2]), p3 = EXP2F(sc[i][3]);
        uint2 w; w.x = pk2f(p0, p1); w.y = pk2f(p2, p3);
        *(uint2*)&Ps[pbase + a * 1024 + pw[i]] = w;
      }
    }

    // phase 2: V fragments, then PV + l row-sum for both q-sets (MFMA burst)
    shortx8 vf[4][2];
#pragma unroll
    for (int nd = 0; nd < 4; nd++) {
      vf[nd][0] = *(const shortx8*)&Vs[p][foff[nd]];
      vf[nd][1] = *(const shortx8*)&Vs[p][foff[nd] ^ 32];
    }
#pragma unroll
    for (int a = 0; a < 2; a++) {
#pragma unroll
      for (int ks = 0; ks < 2; ks++) {
        shortx8 pf = *(const shortx8*)&Ps[pbase + a * 1024 + pr[ks]];
        __builtin_amdgcn_s_setprio(1);
#pragma unroll
        for (int nd = 0; nd < 4; nd++)
          oacc[a][nd] = __builtin_amdgcn_mfma_f32_16x16x32_bf16(vf[nd][ks], pf, oacc[a][nd], 0, 0, 0);
        lacc[a] = __builtin_amdgcn_mfma_f32_16x16x32_bf16(ones, pf, lacc[a], 0, 0, 0);
        __builtin_amdgcn_s_setprio(0);
      }
    }
    __syncthreads();   // buffer p free; prefetch into p^1 drained
  }

  // epilogue: lacc rows identical -> l = lacc[a][0]; O^T cols q, rows d contiguous
#pragma unroll
  for (int a = 0; a < 2; a++) {
    float inv = 1.f / lacc[a][0];
    unsigned short* oPtr = O + (size_t)(b * SEQ + qt * 32 + a * 16 + l15) * 2048 + h * 64 + quad * 4;
#pragma unroll
    for (int nd = 0; nd < 4; nd++) {
      uint2 w;
      w.x = (unsigned)f2bf(oacc[a][nd][0] * inv) | ((unsigned)f2bf(oacc[a][nd][1] * inv) << 16);
      w.y = (unsigned)f2bf(oacc[a][nd][2] * inv) | ((unsigned)f2bf(oacc[a][nd][3] * inv) << 16);
      *(uint2*)(oPtr + nd * 16) = w;
    }
  }
}

extern "C" void kernel_launch(void* const* d_in, const int* in_sizes, int n_in,
                              void* d_out, int out_size, void* d_ws, size_t ws_size,
                              hipStream_t stream) {
  const float* x  = (const float*)d_in[0];
  const float* Wq = (const float*)d_in[1];
  const float* bq = (const float*)d_in[2];
  const float* Wk = (const float*)d_in[3];
  const float* bk = (const float*)d_in[4];
  const float* Wv = (const float*)d_in[5];
  const float* bv = (const float*)d_in[6];
  const float* Wo = (const float*)d_in[7];
  const float* bo = (const float*)d_in[8];
  float* out = (float*)d_out;

  // workspace layout (62,930,944 B total)
  char* ws = (char*)d_ws;
  unsigned short* WTall = (unsigned short*)ws;                          // [3072][2048] 12,582,912
  unsigned short* WoT   = (unsigned short*)(ws + 12582912);             // [2048][2048]  8,388,608
  float*          bqkv  = (float*)(ws + 20971520);                      // [3072] + pad      16384
  unsigned short* xb    = (unsigned short*)(ws + 20987904);             // [4096][2048] 16,777,216
  unsigned short* Qbuf  = (unsigned short*)(ws + 37765120);             // [4096][2048] 16,777,216
  unsigned short* Kbuf  = (unsigned short*)(ws + 54542336);             // [4096][512]   4,194,304
  unsigned short* Vt    = (unsigned short*)(ws + 58736640);             // [16][64][2048] 4,194,304
  unsigned short* Og    = xb;  // attention output reuses xb

  // 1. prep: cast x, transpose+cast weights (Wq pre-scaled), concat bias
  prep_kernel<<<dim3(64, 64, 6), dim3(32, 8), 0, stream>>>(
      x, Wq, Wk, Wv, Wo, bq, bk, bv, WTall, WoT, xb, bqkv);

  // 2. QKV projection: Q -> Qbuf, K -> Kbuf, V -> Vt (transposed)
  gemm_bt<2><<<dim3(32, 24), 256, 0, stream>>>(xb, WTall, bqkv, Qbuf, Kbuf, Vt, 4096, 3072, 2048);

  // 3. grouped flash attention -> Og [4096][2048] bf16
  attn_kernel<<<dim3(64, 8, 2), 256, 0, stream>>>(Qbuf, Kbuf, Vt, Og);

  // 4. output projection -> fp32 out
  gemm_bt<0><<<dim3(32, 16), 256, 0, stream>>>(Og, WoT, bo, out, nullptr, nullptr, 4096, 2048, 2048);
}

// Round 2
// 322.758 us; speedup vs baseline: 1.0518x; 1.0518x over previous
//
#include <hip/hip_runtime.h>
#include <hip/hip_bf16.h>

// GQA block: B=2, S=2048, HID=2048, H=32, G=8, D=64, QPG=4.
// bf16 MFMA 16x16x32; fp32 accumulate. m97-style staging:
// global_load_lds width=16 into unpadded LDS with XOR swizzle
// (chunk_phys = chunk_log ^ (row&7); rows of 64 shorts = 8 chunks of 16B).
// Fragment layouts (HW-verified, learn_hip m89/m120):
//   A-frag:  A[m=lane&15][k=quad*8+j]
//   B-frag:  B[k=quad*8+j][n=lane&15]
//   C/D:     col(n)=lane&15, row(m)=quad*4+reg
// Attention: S^T = K Q^T, O^T = V^T P^T (softmax axis on regs+quads).
// No-max softmax (scores ~N(0,0.9), exp2 has 2^30 headroom, shift-invariant).
// l on the MFMA pipe via register ones-fragment. GQA: block's 4 waves = the 4
// heads of one kv-group sharing one K/V LDS tile.
// R8: 32 q/wave (2 qsets), grid (64,8,2)=1024 blocks.  [regressed: P-LDS
// round-trip overhead per iter amortized over half the MFMA work]
// R9: IN-REGISTER P redistribution — kill the Ps LDS round-trip (the 4.19M
// bank-conflict source + lgkm serialization). QK C-frag -> PV B-frag is a
// 4-lane (quad) butterfly: stage A = 4x v_permlane32_swap_b32 (lane^32,
// VALU pipe), stage B = 4x ds_swizzle xor16 (0x401F) + cndmask selects.
// Element W[i][c]@(b4,b5) -> lane(b4'=b5, b5'=i&1), slot m=2*b4+c.
// LDS 48->32 KB (Ks+Vs dbuf only) => 5 blocks/CU LDS cap; bounds(256,4).

typedef __attribute__((ext_vector_type(8))) short shortx8;
typedef __attribute__((ext_vector_type(4))) float floatx4;

#define SEQ 2048
#define QSC 0.1803368801111204f   // (1/8) * log2(e), folded into Wq/bq

#if __has_builtin(__builtin_amdgcn_exp2f)
#define EXP2F(x) __builtin_amdgcn_exp2f(x)
#else
#define EXP2F(x) __expf((x) * 0.6931471805599453f)
#endif

__device__ __forceinline__ unsigned short f2bf(float f) {      // RNE
  union { float f; unsigned u; } a; a.f = f;
  unsigned u = a.u;
  u += 0x7fffu + ((u >> 16) & 1u);
  return (unsigned short)(u >> 16);
}
__device__ __forceinline__ unsigned pk2f(float lo, float hi) { // fast round
  union { float f; unsigned u; } a, b; a.f = lo; b.f = hi;
  return ((a.u + 0x8000u) >> 16) | (((b.u + 0x8000u) >> 16) << 16);
}

// v_permlane32_swap_b32: a = {a_lo, b_lo}, b = {a_hi, b_hi}
// (swaps upper 32 lanes of a with lower 32 lanes of b; both regs written)
__device__ __forceinline__ void plswap(unsigned &a, unsigned &b) {
  asm("v_permlane32_swap_b32 %0, %1" : "+v"(a), "+v"(b));
}

// async global->LDS, 16B per lane; LDS dst = uniform base + lane*16
__device__ __forceinline__ void gload16(const unsigned short* g, unsigned short* l) {
  __builtin_amdgcn_global_load_lds((const __attribute__((address_space(1))) void*)g,
                                   (__attribute__((address_space(3))) void*)l, 16, 0, 0);
}

// ---------------- prep: cast x, transpose+cast all weights, concat bias ----------
// grid (64,64,6), block (32,8). z: 0=Wq(*QSC) 1=Wk 2=Wv 3=Wo 4=cast-x 5=bias.
__global__ void prep_kernel(const float* __restrict__ x,
                            const float* __restrict__ Wq, const float* __restrict__ Wk,
                            const float* __restrict__ Wv, const float* __restrict__ Wo,
                            const float* __restrict__ bq, const float* __restrict__ bk,
                            const float* __restrict__ bv,
                            unsigned short* __restrict__ WT,
                            unsigned short* __restrict__ WoT,
                            unsigned short* __restrict__ xb,
                            float* __restrict__ bqkv) {
  const int z = blockIdx.z;
  if (z == 4) {                       // cast x -> bf16, 2048 floats per block
    int fb = blockIdx.y * 64 + blockIdx.x;
    int tid = threadIdx.y * 32 + threadIdx.x;
    int i = fb * 2048 + tid * 8;
    float4 v0 = *(const float4*)(x + i);
    float4 v1 = *(const float4*)(x + i + 4);
    ushort4 o0, o1;
    o0.x = f2bf(v0.x); o0.y = f2bf(v0.y); o0.z = f2bf(v0.z); o0.w = f2bf(v0.w);
    o1.x = f2bf(v1.x); o1.y = f2bf(v1.y); o1.z = f2bf(v1.z); o1.w = f2bf(v1.w);
    *(ushort4*)(xb + i) = o0;
    *(ushort4*)(xb + i + 4) = o1;
    return;
  }
  if (z == 5) {                       // concat bias
    int fb = blockIdx.y * 64 + blockIdx.x;
    if (fb >= 12) return;
    int i = fb * 256 + threadIdx.y * 32 + threadIdx.x;
    if (i < 2048) bqkv[i] = bq[i] * QSC;
    else if (i < 2560) bqkv[i] = bk[i - 2048];
    else if (i < 3072) bqkv[i] = bv[i - 2560];
    return;
  }
  const float* W; unsigned short* D; int N; float sc = 1.f;
  if (z == 0)      { W = Wq; D = WT;               N = 2048; sc = QSC; }
  else if (z == 1) { W = Wk; D = WT + 2048 * 2048; N = 512; }
  else if (z == 2) { W = Wv; D = WT + 2560 * 2048; N = 512; }
  else             { W = Wo; D = WoT;              N = 2048; }
  if (blockIdx.x * 32 >= N) return;

  __shared__ float tile[32][33];
  int xx = blockIdx.x * 32 + threadIdx.x;
  int y0 = blockIdx.y * 32;
  for (int i = 0; i < 32; i += 8)
    tile[threadIdx.y + i][threadIdx.x] = W[(size_t)(y0 + threadIdx.y + i) * N + xx];
  __syncthreads();
  int nx = y0 + threadIdx.x;
  int ny = blockIdx.x * 32 + threadIdx.y;
  for (int i = 0; i < 32; i += 8)
    D[(size_t)(ny + i) * 2048 + nx] = f2bf(tile[threadIdx.x][threadIdx.y + i] * sc);
}

// ---------------- bf16 GEMM (m97 structure): C = A @ BT^T + bias ----------------
// 128x128 tile, BK=64, 4 waves (2x2), global_load_lds staging, swizzled LDS.
// MODE 0: fp32 out. MODE 2: QKV split (Q -> Cout bf16, K -> Kbuf, V -> Vt[gb][d][s]).
template <int MODE>
__global__ __launch_bounds__(256) void gemm_bt(const unsigned short* __restrict__ A,
                                               const unsigned short* __restrict__ BT,
                                               const float* __restrict__ bias,
                                               void* __restrict__ Cout,
                                               unsigned short* __restrict__ Kbuf,
                                               unsigned short* __restrict__ Vt,
                                               int M, int N, int K) {
  __shared__ __align__(16) unsigned short As[128 * 64];
  __shared__ __align__(16) unsigned short Bs[128 * 64];
  const int m0 = blockIdx.x * 128, n0 = blockIdx.y * 128;
  const int tid = threadIdx.x;
  const int lane = tid & 63, wave = tid >> 6;
  const int l15 = lane & 15, quad = lane >> 4;
  const int wm = (wave & 1) * 64, wn = (wave >> 1) * 64;

  const int r8 = lane >> 3;
  const int clog = (lane & 7) ^ r8;
  const unsigned short* aSrc = A + (size_t)(m0 + wave * 32 + r8) * K + clog * 8;
  const unsigned short* bSrc = BT + (size_t)(n0 + wave * 32 + r8) * K + clog * 8;
  unsigned short* aDst = &As[wave * 2048];
  unsigned short* bDst = &Bs[wave * 2048];

  const int s = l15 & 7;
  int aoff[4], boff[4];
#pragma unroll
  for (int i = 0; i < 4; i++) aoff[i] = (wm + i * 16 + l15) * 64 + (quad ^ s) * 8;
#pragma unroll
  for (int j = 0; j < 4; j++) boff[j] = (wn + j * 16 + l15) * 64 + (quad ^ s) * 8;

  floatx4 acc[4][4];
#pragma unroll
  for (int i = 0; i < 4; i++)
#pragma unroll
    for (int j = 0; j < 4; j++)
#pragma unroll
      for (int r = 0; r < 4; r++) acc[i][j][r] = 0.f;

  for (int k0 = 0; k0 < K; k0 += 64) {
    __syncthreads();
#pragma unroll
    for (int j = 0; j < 4; j++) {
      gload16(aSrc + (size_t)j * 8 * K + k0, aDst + j * 512);
      gload16(bSrc + (size_t)j * 8 * K + k0, bDst + j * 512);
    }
    __syncthreads();
    {
      shortx8 af[4], bf[4];
#pragma unroll
      for (int i = 0; i < 4; i++) af[i] = *(const shortx8*)&As[aoff[i]];
#pragma unroll
      for (int j = 0; j < 4; j++) bf[j] = *(const shortx8*)&Bs[boff[j]];
#pragma unroll
      for (int i = 0; i < 4; i++)
#pragma unroll
        for (int j = 0; j < 4; j++)
          acc[i][j] = __builtin_amdgcn_mfma_f32_16x16x32_bf16(af[i], bf[j], acc[i][j], 0, 0, 0);
#pragma unroll
      for (int i = 0; i < 4; i++) af[i] = *(const shortx8*)&As[aoff[i] ^ 32];
#pragma unroll
      for (int j = 0; j < 4; j++) bf[j] = *(const shortx8*)&Bs[boff[j] ^ 32];
#pragma unroll
      for (int i = 0; i < 4; i++)
#pragma unroll
        for (int j = 0; j < 4; j++)
          acc[i][j] = __builtin_amdgcn_mfma_f32_16x16x32_bf16(af[i], bf[j], acc[i][j], 0, 0, 0);
    }
  }

#pragma unroll
  for (int i = 0; i < 4; i++) {
#pragma unroll
    for (int j = 0; j < 4; j++) {
      int col = n0 + wn + j * 16 + l15;
      float bv = bias[col];
#pragma unroll
      for (int r = 0; r < 4; r++) {
        int row = m0 + wm + i * 16 + quad * 4 + r;
        float v = acc[i][j][r] + bv;
        if (MODE == 0) {
          ((float*)Cout)[(size_t)row * N + col] = v;
        } else {
          if (col < 2048) {
            ((unsigned short*)Cout)[(size_t)row * 2048 + col] = f2bf(v);
          } else if (col < 2560) {
            Kbuf[(size_t)row * 512 + (col - 2048)] = f2bf(v);
          } else {
            int g = (col - 2560) >> 6, d = (col - 2560) & 63;
            int b = row >> 11, sidx = row & 2047;
            Vt[(size_t)(((g << 1) | b) * 64 + d) * 2048 + sidx] = f2bf(v);
          }
        }
      }
    }
  }
}

// ---------------- flash attention (group-shared K/V, dbuf, in-register P) --------
// grid (S/32=64, G=8, B=2); wave w = head g*4+w. Each wave: 32 q rows as 2
// q-sets of 16. K/V dbuf (1 barrier/tile). P stays in registers: QK C-frag is
// redistributed to PV B-frag via permlane32_swap (lane^32) + ds_swizzle xor16.
// LDS 32 KB -> 5 blocks/CU cap; launch_bounds(256,4) keeps VGPR<=128.
__global__ __launch_bounds__(256, 4) void attn_kernel(const unsigned short* __restrict__ Qb,
                                                      const unsigned short* __restrict__ Kb,
                                                      const unsigned short* __restrict__ Vt,
                                                      unsigned short* __restrict__ O) {
  const int qt = blockIdx.x, g = blockIdx.y, b = blockIdx.z;
  const int tid = threadIdx.x;
  const int lane = tid & 63, wave = tid >> 6;
  const int h = g * 4 + wave;
  const int l15 = lane & 15, quad = lane >> 4;

  __shared__ __align__(16) unsigned short Ks[2][64 * 64];  // [t][d] swizzled, 2x8 KB
  __shared__ __align__(16) unsigned short Vs[2][64 * 64];  // [d][t] swizzled, 2x8 KB

  // Q fragments for 2 q-sets (32 q rows per wave)
  shortx8 qf[2][2];
  {
    const unsigned short* qp = Qb + (size_t)(b * SEQ + qt * 32 + l15) * 2048 + h * 64 + quad * 8;
#pragma unroll
    for (int a = 0; a < 2; a++) {
      qf[a][0] = *(const shortx8*)(qp + (size_t)a * 16 * 2048);
      qf[a][1] = *(const shortx8*)(qp + (size_t)a * 16 * 2048 + 32);
    }
  }

  // staging: wave stages rows wave*16..+15 of each tile (2 issues of 8 rows)
  const int r8 = lane >> 3;
  const int clog = (lane & 7) ^ r8;
  const unsigned short* kSrc = Kb + ((size_t)b * SEQ + wave * 16 + r8) * 512 + g * 64 + clog * 8;
  const unsigned short* vSrc = Vt + ((size_t)((g * 2 + b) * 64 + wave * 16 + r8)) * 2048 + clog * 8;

  const int s = l15 & 7;
  int foff[4];
#pragma unroll
  for (int i = 0; i < 4; i++) foff[i] = (i * 16 + l15) * 64 + ((quad ^ s) * 8);

  const bool hb4 = (quad & 1) != 0;   // lane bit 4

  shortx8 ones;
#pragma unroll
  for (int j = 0; j < 8; j++) ones[j] = (short)0x3F80;     // bf16 1.0

  floatx4 oacc[2][4], lacc[2];
#pragma unroll
  for (int a = 0; a < 2; a++) {
#pragma unroll
    for (int r = 0; r < 4; r++) lacc[a][r] = 0.f;
#pragma unroll
    for (int nd = 0; nd < 4; nd++)
#pragma unroll
      for (int r = 0; r < 4; r++) oacc[a][nd][r] = 0.f;
  }

  // prologue: stage tile 0 into buffer 0
  {
    unsigned short* kD = &Ks[0][wave * 1024];
    unsigned short* vD = &Vs[0][wave * 1024];
    gload16(kSrc, kD);
    gload16(kSrc + (size_t)8 * 512, kD + 512);
    gload16(vSrc, vD);
    gload16(vSrc + (size_t)8 * 2048, vD + 512);
  }
  __syncthreads();

  for (int it = 0; it < SEQ / 64; it++) {
    const int p = it & 1;
    // prefetch next tile into the other buffer (async; drained by the
    // end-of-iter barrier, ~1 tile of compute later)
    if (it < SEQ / 64 - 1) {
      const size_t t1 = (size_t)(it + 1) * 64;
      unsigned short* kD = &Ks[p ^ 1][wave * 1024];
      unsigned short* vD = &Vs[p ^ 1][wave * 1024];
      gload16(kSrc + t1 * 512, kD);
      gload16(kSrc + (t1 + 8) * 512, kD + 512);
      gload16(vSrc + t1, vD);
      gload16(vSrc + (size_t)8 * 2048 + t1, vD + 512);
    }

    // K fragments (reused by both q-sets)
    shortx8 kf[4][2];
#pragma unroll
    for (int i = 0; i < 4; i++) {
      kf[i][0] = *(const shortx8*)&Ks[p][foff[i]];
      kf[i][1] = *(const shortx8*)&Ks[p][foff[i] ^ 32];
    }

    // phase 1: per q-set QK^T -> exp -> in-register butterfly -> PV B-frags.
    // sc[i][r] = score[t = i*16 + quad*4 + r][q = l15]; pack pairs to bf16:
    // wq[i][c] = pair(t = 16i + 4quad + 2c). Target: pfr[a][ks].u32[m] =
    // pair(t = 32ks + 8quad + 2m). Route: W[i][c]@(b4,b5) -> lane(b4'=b5,
    // b5'=i&1), slot m = 2*b4 + c, ks = i>>1.
    shortx8 pfr[2][2];
#pragma unroll
    for (int a = 0; a < 2; a++) {
      floatx4 sc[4];
      __builtin_amdgcn_s_setprio(1);
#pragma unroll
      for (int i = 0; i < 4; i++) {
        floatx4 c = {0.f, 0.f, 0.f, 0.f};
        c = __builtin_amdgcn_mfma_f32_16x16x32_bf16(kf[i][0], qf[a][0], c, 0, 0, 0);
        c = __builtin_amdgcn_mfma_f32_16x16x32_bf16(kf[i][1], qf[a][1], c, 0, 0, 0);
        sc[i] = c;
      }
      __builtin_amdgcn_s_setprio(0);
      unsigned e0a = pk2f(EXP2F(sc[0][0]), EXP2F(sc[0][1]));
      unsigned e0b = pk2f(EXP2F(sc[0][2]), EXP2F(sc[0][3]));
      unsigned e1a = pk2f(EXP2F(sc[1][0]), EXP2F(sc[1][1]));
      unsigned e1b = pk2f(EXP2F(sc[1][2]), EXP2F(sc[1][3]));
      unsigned e2a = pk2f(EXP2F(sc[2][0]), EXP2F(sc[2][1]));
      unsigned e2b = pk2f(EXP2F(sc[2][2]), EXP2F(sc[2][3]));
      unsigned e3a = pk2f(EXP2F(sc[3][0]), EXP2F(sc[3][1]));
      unsigned e3b = pk2f(EXP2F(sc[3][2]), EXP2F(sc[3][3]));
      // stage A: exchange across lane^32. After each swap:
      //   first  = {lo: own W[even], hi: partner W[odd]}  (dest b4' = 0 family)
      //   second = {lo: partner W[even], hi: own W[odd]}  (dest b4' = 1 family)
      plswap(e0a, e1a);   // i in {0,1}, c=0
      plswap(e0b, e1b);   // i in {0,1}, c=1
      plswap(e2a, e3a);   // i in {2,3}, c=0
      plswap(e2b, e3b);   // i in {2,3}, c=1
      // stage B: exchange across lane^16 (ds_swizzle xor16) + selects
      unsigned x0 = hb4 ? e0a : e1a;
      unsigned y0 = hb4 ? e0b : e1b;
      unsigned x1 = hb4 ? e2a : e3a;
      unsigned y1 = hb4 ? e2b : e3b;
      x0 = (unsigned)__builtin_amdgcn_ds_swizzle((int)x0, 0x401F);
      y0 = (unsigned)__builtin_amdgcn_ds_swizzle((int)y0, 0x401F);
      x1 = (unsigned)__builtin_amdgcn_ds_swizzle((int)x1, 0x401F);
      y1 = (unsigned)__builtin_amdgcn_ds_swizzle((int)y1, 0x401F);
      union { unsigned u[4]; shortx8 v; } P0, P1;
      P0.u[0] = hb4 ? x0 : e0a;  P0.u[1] = hb4 ? y0 : e0b;
      P0.u[2] = hb4 ? e1a : x0;  P0.u[3] = hb4 ? e1b : y0;
      P1.u[0] = hb4 ? x1 : e2a;  P1.u[1] = hb4 ? y1 : e2b;
      P1.u[2] = hb4 ? e3a : x1;  P1.u[3] = hb4 ? e3b : y1;
      pfr[a][0] = P0.v;
      pfr[a][1] = P1.v;
    }

    // phase 2: V fragments, then PV + l row-sum for both q-sets (MFMA burst)
    shortx8 vf[4][2];
#pragma unroll
    for (int nd = 0; nd < 4; nd++) {
      vf[nd][0] = *(const shortx8*)&Vs[p][foff[nd]];
      vf[nd][1] = *(const shortx8*)&Vs[p][foff[nd] ^ 32];
    }
#pragma unroll
    for (int a = 0; a < 2; a++) {
#pragma unroll
      for (int ks = 0; ks < 2; ks++) {
        shortx8 pf = pfr[a][ks];
        __builtin_amdgcn_s_setprio(1);
#pragma unroll
        for (int nd = 0; nd < 4; nd++)
          oacc[a][nd] = __builtin_amdgcn_mfma_f32_16x16x32_bf16(vf[nd][ks], pf, oacc[a][nd], 0, 0, 0);
        lacc[a] = __builtin_amdgcn_mfma_f32_16x16x32_bf16(ones, pf, lacc[a], 0, 0, 0);
        __builtin_amdgcn_s_setprio(0);
      }
    }
    __syncthreads();   // buffer p free; prefetch into p^1 drained
  }

  // epilogue: lacc rows identical -> l = lacc[a][0]; O^T cols q, rows d contiguous
#pragma unroll
  for (int a = 0; a < 2; a++) {
    float inv = 1.f / lacc[a][0];
    unsigned short* oPtr = O + (size_t)(b * SEQ + qt * 32 + a * 16 + l15) * 2048 + h * 64 + quad * 4;
#pragma unroll
    for (int nd = 0; nd < 4; nd++) {
      uint2 w;
      w.x = (unsigned)f2bf(oacc[a][nd][0] * inv) | ((unsigned)f2bf(oacc[a][nd][1] * inv) << 16);
      w.y = (unsigned)f2bf(oacc[a][nd][2] * inv) | ((unsigned)f2bf(oacc[a][nd][3] * inv) << 16);
      *(uint2*)(oPtr + nd * 16) = w;
    }
  }
}

extern "C" void kernel_launch(void* const* d_in, const int* in_sizes, int n_in,
                              void* d_out, int out_size, void* d_ws, size_t ws_size,
                              hipStream_t stream) {
  const float* x  = (const float*)d_in[0];
  const float* Wq = (const float*)d_in[1];
  const float* bq = (const float*)d_in[2];
  const float* Wk = (const float*)d_in[3];
  const float* bk = (const float*)d_in[4];
  const float* Wv = (const float*)d_in[5];
  const float* bv = (const float*)d_in[6];
  const float* Wo = (const float*)d_in[7];
  const float* bo = (const float*)d_in[8];
  float* out = (float*)d_out;

  // workspace layout (62,930,944 B total)
  char* ws = (char*)d_ws;
  unsigned short* WTall = (unsigned short*)ws;                          // [3072][2048] 12,582,912
  unsigned short* WoT   = (unsigned short*)(ws + 12582912);             // [2048][2048]  8,388,608
  float*          bqkv  = (float*)(ws + 20971520);                      // [3072] + pad      16384
  unsigned short* xb    = (unsigned short*)(ws + 20987904);             // [4096][2048] 16,777,216
  unsigned short* Qbuf  = (unsigned short*)(ws + 37765120);             // [4096][2048] 16,777,216
  unsigned short* Kbuf  = (unsigned short*)(ws + 54542336);             // [4096][512]   4,194,304
  unsigned short* Vt    = (unsigned short*)(ws + 58736640);             // [16][64][2048] 4,194,304
  unsigned short* Og    = xb;  // attention output reuses xb

  // 1. prep: cast x, transpose+cast weights (Wq pre-scaled), concat bias
  prep_kernel<<<dim3(64, 64, 6), dim3(32, 8), 0, stream>>>(
      x, Wq, Wk, Wv, Wo, bq, bk, bv, WTall, WoT, xb, bqkv);

  // 2. QKV projection: Q -> Qbuf, K -> Kbuf, V -> Vt (transposed)
  gemm_bt<2><<<dim3(32, 24), 256, 0, stream>>>(xb, WTall, bqkv, Qbuf, Kbuf, Vt, 4096, 3072, 2048);

  // 3. grouped flash attention -> Og [4096][2048] bf16
  attn_kernel<<<dim3(64, 8, 2), 256, 0, stream>>>(Qbuf, Kbuf, Vt, Og);

  // 4. output projection -> fp32 out
  gemm_bt<0><<<dim3(32, 16), 256, 0, stream>>>(Og, WoT, bo, out, nullptr, nullptr, 4096, 2048, 2048);
}

// Round 3
// 304.837 us; speedup vs baseline: 1.1136x; 1.0588x over previous
//
#include <hip/hip_runtime.h>
#include <hip/hip_bf16.h>

// GQA block: B=2, S=2048, HID=2048, H=32, G=8, D=64, QPG=4.
// bf16 MFMA 16x16x32; fp32 accumulate. m97-style staging:
// global_load_lds width=16 into unpadded LDS with XOR swizzle
// (chunk_phys = chunk_log ^ (row&7); rows of 64 shorts = 8 chunks of 16B).
// Fragment layouts (HW-verified, learn_hip m89/m120):
//   A-frag:  A[m=lane&15][k=quad*8+j]
//   B-frag:  B[k=quad*8+j][n=lane&15]
//   C/D:     col(n)=lane&15, row(m)=quad*4+reg
// Attention: S^T = K Q^T, O^T = V^T P^T (softmax axis on regs+quads).
// No-max softmax (scores ~N(0,0.9), exp2 has 2^30 headroom, shift-invariant).
// l on the MFMA pipe via register ones-fragment. GQA: block's 4 waves = the 4
// heads of one kv-group sharing one K/V LDS tile.
// R9: in-register P redistribution (permlane32_swap + ds_swizzle butterfly);
//     bank conflicts 4.19M -> 0, attn 108 -> 96 us. VALUBusy 54% > Mfma 34%:
//     the pack+butterfly VALU chain is now the bottleneck.
// R10: VALU diet. (a) pk2f (3-5 ops) -> v_cvt_pk_bf16_f32 (1 op, RNE).
//     (b) stage B: two-register v_permlane16_swap_b32 on (F0c,F1c) replaces
//     select + ds_swizzle + 2 selects — element-traced vs R9 dataflow: for
//     dest reg m (c=m&1, src_b4=m>>1) at lane (b4',b5'), new_F{m>>1}c holds
//     E[2ks+b5'][c] @ (b4=m>>1, b5=b4') exactly. Zero selects, zero LDS ops.
//     Butterfly+pack: ~56 VALU + 4 LDS -> 16 VALU per q-set.

typedef __attribute__((ext_vector_type(8))) short shortx8;
typedef __attribute__((ext_vector_type(4))) float floatx4;

#define SEQ 2048
#define QSC 0.1803368801111204f   // (1/8) * log2(e), folded into Wq/bq

#if __has_builtin(__builtin_amdgcn_exp2f)
#define EXP2F(x) __builtin_amdgcn_exp2f(x)
#else
#define EXP2F(x) __expf((x) * 0.6931471805599453f)
#endif

__device__ __forceinline__ unsigned short f2bf(float f) {      // RNE
  union { float f; unsigned u; } a; a.f = f;
  unsigned u = a.u;
  u += 0x7fffu + ((u >> 16) & 1u);
  return (unsigned short)(u >> 16);
}

// packed f32x2 -> bf16x2 (RNE), single instruction
__device__ __forceinline__ unsigned cvtpkbf(float lo, float hi) {
  unsigned r;
  asm("v_cvt_pk_bf16_f32 %0, %1, %2" : "=v"(r) : "v"(lo), "v"(hi));
  return r;
}

// v_permlane32_swap_b32: a = {a_lo32, b_lo32}, b = {a_hi32, b_hi32}
__device__ __forceinline__ void plswap(unsigned &a, unsigned &b) {
  asm("v_permlane32_swap_b32 %0, %1" : "+v"(a), "+v"(b));
}
// v_permlane16_swap_b32: within each 32-half, a = {a_lo16, b_lo16}, b = {a_hi16, b_hi16}
__device__ __forceinline__ void pl16swap(unsigned &a, unsigned &b) {
  asm("v_permlane16_swap_b32 %0, %1" : "+v"(a), "+v"(b));
}

// async global->LDS, 16B per lane; LDS dst = uniform base + lane*16
__device__ __forceinline__ void gload16(const unsigned short* g, unsigned short* l) {
  __builtin_amdgcn_global_load_lds((const __attribute__((address_space(1))) void*)g,
                                   (__attribute__((address_space(3))) void*)l, 16, 0, 0);
}

// ---------------- prep: cast x, transpose+cast all weights, concat bias ----------
// grid (64,64,6), block (32,8). z: 0=Wq(*QSC) 1=Wk 2=Wv 3=Wo 4=cast-x 5=bias.
__global__ void prep_kernel(const float* __restrict__ x,
                            const float* __restrict__ Wq, const float* __restrict__ Wk,
                            const float* __restrict__ Wv, const float* __restrict__ Wo,
                            const float* __restrict__ bq, const float* __restrict__ bk,
                            const float* __restrict__ bv,
                            unsigned short* __restrict__ WT,
                            unsigned short* __restrict__ WoT,
                            unsigned short* __restrict__ xb,
                            float* __restrict__ bqkv) {
  const int z = blockIdx.z;
  if (z == 4) {                       // cast x -> bf16, 2048 floats per block
    int fb = blockIdx.y * 64 + blockIdx.x;
    int tid = threadIdx.y * 32 + threadIdx.x;
    int i = fb * 2048 + tid * 8;
    float4 v0 = *(const float4*)(x + i);
    float4 v1 = *(const float4*)(x + i + 4);
    ushort4 o0, o1;
    o0.x = f2bf(v0.x); o0.y = f2bf(v0.y); o0.z = f2bf(v0.z); o0.w = f2bf(v0.w);
    o1.x = f2bf(v1.x); o1.y = f2bf(v1.y); o1.z = f2bf(v1.z); o1.w = f2bf(v1.w);
    *(ushort4*)(xb + i) = o0;
    *(ushort4*)(xb + i + 4) = o1;
    return;
  }
  if (z == 5) {                       // concat bias
    int fb = blockIdx.y * 64 + blockIdx.x;
    if (fb >= 12) return;
    int i = fb * 256 + threadIdx.y * 32 + threadIdx.x;
    if (i < 2048) bqkv[i] = bq[i] * QSC;
    else if (i < 2560) bqkv[i] = bk[i - 2048];
    else if (i < 3072) bqkv[i] = bv[i - 2560];
    return;
  }
  const float* W; unsigned short* D; int N; float sc = 1.f;
  if (z == 0)      { W = Wq; D = WT;               N = 2048; sc = QSC; }
  else if (z == 1) { W = Wk; D = WT + 2048 * 2048; N = 512; }
  else if (z == 2) { W = Wv; D = WT + 2560 * 2048; N = 512; }
  else             { W = Wo; D = WoT;              N = 2048; }
  if (blockIdx.x * 32 >= N) return;

  __shared__ float tile[32][33];
  int xx = blockIdx.x * 32 + threadIdx.x;
  int y0 = blockIdx.y * 32;
  for (int i = 0; i < 32; i += 8)
    tile[threadIdx.y + i][threadIdx.x] = W[(size_t)(y0 + threadIdx.y + i) * N + xx];
  __syncthreads();
  int nx = y0 + threadIdx.x;
  int ny = blockIdx.x * 32 + threadIdx.y;
  for (int i = 0; i < 32; i += 8)
    D[(size_t)(ny + i) * 2048 + nx] = f2bf(tile[threadIdx.x][threadIdx.y + i] * sc);
}

// ---------------- bf16 GEMM (m97 structure): C = A @ BT^T + bias ----------------
// 128x128 tile, BK=64, 4 waves (2x2), global_load_lds staging, swizzled LDS.
// MODE 0: fp32 out. MODE 2: QKV split (Q -> Cout bf16, K -> Kbuf, V -> Vt[gb][d][s]).
template <int MODE>
__global__ __launch_bounds__(256) void gemm_bt(const unsigned short* __restrict__ A,
                                               const unsigned short* __restrict__ BT,
                                               const float* __restrict__ bias,
                                               void* __restrict__ Cout,
                                               unsigned short* __restrict__ Kbuf,
                                               unsigned short* __restrict__ Vt,
                                               int M, int N, int K) {
  __shared__ __align__(16) unsigned short As[128 * 64];
  __shared__ __align__(16) unsigned short Bs[128 * 64];
  const int m0 = blockIdx.x * 128, n0 = blockIdx.y * 128;
  const int tid = threadIdx.x;
  const int lane = tid & 63, wave = tid >> 6;
  const int l15 = lane & 15, quad = lane >> 4;
  const int wm = (wave & 1) * 64, wn = (wave >> 1) * 64;

  const int r8 = lane >> 3;
  const int clog = (lane & 7) ^ r8;
  const unsigned short* aSrc = A + (size_t)(m0 + wave * 32 + r8) * K + clog * 8;
  const unsigned short* bSrc = BT + (size_t)(n0 + wave * 32 + r8) * K + clog * 8;
  unsigned short* aDst = &As[wave * 2048];
  unsigned short* bDst = &Bs[wave * 2048];

  const int s = l15 & 7;
  int aoff[4], boff[4];
#pragma unroll
  for (int i = 0; i < 4; i++) aoff[i] = (wm + i * 16 + l15) * 64 + (quad ^ s) * 8;
#pragma unroll
  for (int j = 0; j < 4; j++) boff[j] = (wn + j * 16 + l15) * 64 + (quad ^ s) * 8;

  floatx4 acc[4][4];
#pragma unroll
  for (int i = 0; i < 4; i++)
#pragma unroll
    for (int j = 0; j < 4; j++)
#pragma unroll
      for (int r = 0; r < 4; r++) acc[i][j][r] = 0.f;

  for (int k0 = 0; k0 < K; k0 += 64) {
    __syncthreads();
#pragma unroll
    for (int j = 0; j < 4; j++) {
      gload16(aSrc + (size_t)j * 8 * K + k0, aDst + j * 512);
      gload16(bSrc + (size_t)j * 8 * K + k0, bDst + j * 512);
    }
    __syncthreads();
    {
      shortx8 af[4], bf[4];
#pragma unroll
      for (int i = 0; i < 4; i++) af[i] = *(const shortx8*)&As[aoff[i]];
#pragma unroll
      for (int j = 0; j < 4; j++) bf[j] = *(const shortx8*)&Bs[boff[j]];
#pragma unroll
      for (int i = 0; i < 4; i++)
#pragma unroll
        for (int j = 0; j < 4; j++)
          acc[i][j] = __builtin_amdgcn_mfma_f32_16x16x32_bf16(af[i], bf[j], acc[i][j], 0, 0, 0);
#pragma unroll
      for (int i = 0; i < 4; i++) af[i] = *(const shortx8*)&As[aoff[i] ^ 32];
#pragma unroll
      for (int j = 0; j < 4; j++) bf[j] = *(const shortx8*)&Bs[boff[j] ^ 32];
#pragma unroll
      for (int i = 0; i < 4; i++)
#pragma unroll
        for (int j = 0; j < 4; j++)
          acc[i][j] = __builtin_amdgcn_mfma_f32_16x16x32_bf16(af[i], bf[j], acc[i][j], 0, 0, 0);
    }
  }

#pragma unroll
  for (int i = 0; i < 4; i++) {
#pragma unroll
    for (int j = 0; j < 4; j++) {
      int col = n0 + wn + j * 16 + l15;
      float bv = bias[col];
#pragma unroll
      for (int r = 0; r < 4; r++) {
        int row = m0 + wm + i * 16 + quad * 4 + r;
        float v = acc[i][j][r] + bv;
        if (MODE == 0) {
          ((float*)Cout)[(size_t)row * N + col] = v;
        } else {
          if (col < 2048) {
            ((unsigned short*)Cout)[(size_t)row * 2048 + col] = f2bf(v);
          } else if (col < 2560) {
            Kbuf[(size_t)row * 512 + (col - 2048)] = f2bf(v);
          } else {
            int g = (col - 2560) >> 6, d = (col - 2560) & 63;
            int b = row >> 11, sidx = row & 2047;
            Vt[(size_t)(((g << 1) | b) * 64 + d) * 2048 + sidx] = f2bf(v);
          }
        }
      }
    }
  }
}

// ---------------- flash attention (group-shared K/V, dbuf, in-register P) --------
// grid (S/32=64, G=8, B=2); wave w = head g*4+w. Each wave: 32 q rows as 2
// q-sets of 16. K/V dbuf (1 barrier/tile). P stays in registers: QK C-frag is
// redistributed to PV B-frag via permlane32_swap then permlane16_swap (pure
// VALU butterfly, zero selects / LDS ops). LDS 32 KB -> 5 blocks/CU cap.
__global__ __launch_bounds__(256, 4) void attn_kernel(const unsigned short* __restrict__ Qb,
                                                      const unsigned short* __restrict__ Kb,
                                                      const unsigned short* __restrict__ Vt,
                                                      unsigned short* __restrict__ O) {
  const int qt = blockIdx.x, g = blockIdx.y, b = blockIdx.z;
  const int tid = threadIdx.x;
  const int lane = tid & 63, wave = tid >> 6;
  const int h = g * 4 + wave;
  const int l15 = lane & 15, quad = lane >> 4;

  __shared__ __align__(16) unsigned short Ks[2][64 * 64];  // [t][d] swizzled, 2x8 KB
  __shared__ __align__(16) unsigned short Vs[2][64 * 64];  // [d][t] swizzled, 2x8 KB

  // Q fragments for 2 q-sets (32 q rows per wave)
  shortx8 qf[2][2];
  {
    const unsigned short* qp = Qb + (size_t)(b * SEQ + qt * 32 + l15) * 2048 + h * 64 + quad * 8;
#pragma unroll
    for (int a = 0; a < 2; a++) {
      qf[a][0] = *(const shortx8*)(qp + (size_t)a * 16 * 2048);
      qf[a][1] = *(const shortx8*)(qp + (size_t)a * 16 * 2048 + 32);
    }
  }

  // staging: wave stages rows wave*16..+15 of each tile (2 issues of 8 rows)
  const int r8 = lane >> 3;
  const int clog = (lane & 7) ^ r8;
  const unsigned short* kSrc = Kb + ((size_t)b * SEQ + wave * 16 + r8) * 512 + g * 64 + clog * 8;
  const unsigned short* vSrc = Vt + ((size_t)((g * 2 + b) * 64 + wave * 16 + r8)) * 2048 + clog * 8;

  const int s = l15 & 7;
  int foff[4];
#pragma unroll
  for (int i = 0; i < 4; i++) foff[i] = (i * 16 + l15) * 64 + ((quad ^ s) * 8);

  shortx8 ones;
#pragma unroll
  for (int j = 0; j < 8; j++) ones[j] = (short)0x3F80;     // bf16 1.0

  floatx4 oacc[2][4], lacc[2];
#pragma unroll
  for (int a = 0; a < 2; a++) {
#pragma unroll
    for (int r = 0; r < 4; r++) lacc[a][r] = 0.f;
#pragma unroll
    for (int nd = 0; nd < 4; nd++)
#pragma unroll
      for (int r = 0; r < 4; r++) oacc[a][nd][r] = 0.f;
  }

  // prologue: stage tile 0 into buffer 0
  {
    unsigned short* kD = &Ks[0][wave * 1024];
    unsigned short* vD = &Vs[0][wave * 1024];
    gload16(kSrc, kD);
    gload16(kSrc + (size_t)8 * 512, kD + 512);
    gload16(vSrc, vD);
    gload16(vSrc + (size_t)8 * 2048, vD + 512);
  }
  __syncthreads();

  for (int it = 0; it < SEQ / 64; it++) {
    const int p = it & 1;
    // prefetch next tile into the other buffer (async; drained by the
    // end-of-iter barrier, ~1 tile of compute later)
    if (it < SEQ / 64 - 1) {
      const size_t t1 = (size_t)(it + 1) * 64;
      unsigned short* kD = &Ks[p ^ 1][wave * 1024];
      unsigned short* vD = &Vs[p ^ 1][wave * 1024];
      gload16(kSrc + t1 * 512, kD);
      gload16(kSrc + (t1 + 8) * 512, kD + 512);
      gload16(vSrc + t1, vD);
      gload16(vSrc + (size_t)8 * 2048 + t1, vD + 512);
    }

    // K fragments (reused by both q-sets)
    shortx8 kf[4][2];
#pragma unroll
    for (int i = 0; i < 4; i++) {
      kf[i][0] = *(const shortx8*)&Ks[p][foff[i]];
      kf[i][1] = *(const shortx8*)&Ks[p][foff[i] ^ 32];
    }

    // phase 1: per q-set QK^T -> exp -> pure-VALU butterfly -> PV B-frags.
    // sc[i][r] = score[t = i*16 + quad*4 + r][q = l15]. Pack pairs (cvt_pk):
    // E[i][c] = pair(t = 16i + 4quad + 2c). Target: pfr[a][ks].u32[m] =
    // pair(t = 32ks + 8quad + 2m), i.e. element W[i][c]@(b4,b5) must land at
    // lane(b4'=b5, b5'=i&1), slot m=2*b4+c, ks=i>>1.
    // Stage A plswap(E[2ks],E[2ks+1]) routes b5'; stage B pl16swap(F0c,F1c)
    // routes b4: new_F{m>>1}c @ lane(b4',b5') = E[2ks+b5'][c]@(m>>1, b4'). QED.
    shortx8 pfr[2][2];
#pragma unroll
    for (int a = 0; a < 2; a++) {
      floatx4 sc[4];
      __builtin_amdgcn_s_setprio(1);
#pragma unroll
      for (int i = 0; i < 4; i++) {
        floatx4 c = {0.f, 0.f, 0.f, 0.f};
        c = __builtin_amdgcn_mfma_f32_16x16x32_bf16(kf[i][0], qf[a][0], c, 0, 0, 0);
        c = __builtin_amdgcn_mfma_f32_16x16x32_bf16(kf[i][1], qf[a][1], c, 0, 0, 0);
        sc[i] = c;
      }
      __builtin_amdgcn_s_setprio(0);
      unsigned E00 = cvtpkbf(EXP2F(sc[0][0]), EXP2F(sc[0][1]));
      unsigned E01 = cvtpkbf(EXP2F(sc[0][2]), EXP2F(sc[0][3]));
      unsigned E10 = cvtpkbf(EXP2F(sc[1][0]), EXP2F(sc[1][1]));
      unsigned E11 = cvtpkbf(EXP2F(sc[1][2]), EXP2F(sc[1][3]));
      unsigned E20 = cvtpkbf(EXP2F(sc[2][0]), EXP2F(sc[2][1]));
      unsigned E21 = cvtpkbf(EXP2F(sc[2][2]), EXP2F(sc[2][3]));
      unsigned E30 = cvtpkbf(EXP2F(sc[3][0]), EXP2F(sc[3][1]));
      unsigned E31 = cvtpkbf(EXP2F(sc[3][2]), EXP2F(sc[3][3]));
      // stage A: lane^32 routing (b5' = i&1)
      plswap(E00, E10); plswap(E01, E11);   // ks=0
      plswap(E20, E30); plswap(E21, E31);   // ks=1
      // stage B: lane^16 routing (src b4 = m>>1) — no selects needed
      pl16swap(E00, E10); pl16swap(E01, E11);
      pl16swap(E20, E30); pl16swap(E21, E31);
      union { unsigned u[4]; shortx8 v; } P0, P1;
      P0.u[0] = E00; P0.u[1] = E01; P0.u[2] = E10; P0.u[3] = E11;
      P1.u[0] = E20; P1.u[1] = E21; P1.u[2] = E30; P1.u[3] = E31;
      pfr[a][0] = P0.v;
      pfr[a][1] = P1.v;
    }

    // phase 2: V fragments, then PV + l row-sum for both q-sets (MFMA burst)
    shortx8 vf[4][2];
#pragma unroll
    for (int nd = 0; nd < 4; nd++) {
      vf[nd][0] = *(const shortx8*)&Vs[p][foff[nd]];
      vf[nd][1] = *(const shortx8*)&Vs[p][foff[nd] ^ 32];
    }
#pragma unroll
    for (int a = 0; a < 2; a++) {
#pragma unroll
      for (int ks = 0; ks < 2; ks++) {
        shortx8 pf = pfr[a][ks];
        __builtin_amdgcn_s_setprio(1);
#pragma unroll
        for (int nd = 0; nd < 4; nd++)
          oacc[a][nd] = __builtin_amdgcn_mfma_f32_16x16x32_bf16(vf[nd][ks], pf, oacc[a][nd], 0, 0, 0);
        lacc[a] = __builtin_amdgcn_mfma_f32_16x16x32_bf16(ones, pf, lacc[a], 0, 0, 0);
        __builtin_amdgcn_s_setprio(0);
      }
    }
    __syncthreads();   // buffer p free; prefetch into p^1 drained
  }

  // epilogue: lacc rows identical -> l = lacc[a][0]; O^T cols q, rows d contiguous
#pragma unroll
  for (int a = 0; a < 2; a++) {
    float inv = 1.f / lacc[a][0];
    unsigned short* oPtr = O + (size_t)(b * SEQ + qt * 32 + a * 16 + l15) * 2048 + h * 64 + quad * 4;
#pragma unroll
    for (int nd = 0; nd < 4; nd++) {
      uint2 w;
      w.x = (unsigned)f2bf(oacc[a][nd][0] * inv) | ((unsigned)f2bf(oacc[a][nd][1] * inv) << 16);
      w.y = (unsigned)f2bf(oacc[a][nd][2] * inv) | ((unsigned)f2bf(oacc[a][nd][3] * inv) << 16);
      *(uint2*)(oPtr + nd * 16) = w;
    }
  }
}

extern "C" void kernel_launch(void* const* d_in, const int* in_sizes, int n_in,
                              void* d_out, int out_size, void* d_ws, size_t ws_size,
                              hipStream_t stream) {
  const float* x  = (const float*)d_in[0];
  const float* Wq = (const float*)d_in[1];
  const float* bq = (const float*)d_in[2];
  const float* Wk = (const float*)d_in[3];
  const float* bk = (const float*)d_in[4];
  const float* Wv = (const float*)d_in[5];
  const float* bv = (const float*)d_in[6];
  const float* Wo = (const float*)d_in[7];
  const float* bo = (const float*)d_in[8];
  float* out = (float*)d_out;

  // workspace layout (62,930,944 B total)
  char* ws = (char*)d_ws;
  unsigned short* WTall = (unsigned short*)ws;                          // [3072][2048] 12,582,912
  unsigned short* WoT   = (unsigned short*)(ws + 12582912);             // [2048][2048]  8,388,608
  float*          bqkv  = (float*)(ws + 20971520);                      // [3072] + pad      16384
  unsigned short* xb    = (unsigned short*)(ws + 20987904);             // [4096][2048] 16,777,216
  unsigned short* Qbuf  = (unsigned short*)(ws + 37765120);             // [4096][2048] 16,777,216
  unsigned short* Kbuf  = (unsigned short*)(ws + 54542336);             // [4096][512]   4,194,304
  unsigned short* Vt    = (unsigned short*)(ws + 58736640);             // [16][64][2048] 4,194,304
  unsigned short* Og    = xb;  // attention output reuses xb

  // 1. prep: cast x, transpose+cast weights (Wq pre-scaled), concat bias
  prep_kernel<<<dim3(64, 64, 6), dim3(32, 8), 0, stream>>>(
      x, Wq, Wk, Wv, Wo, bq, bk, bv, WTall, WoT, xb, bqkv);

  // 2. QKV projection: Q -> Qbuf, K -> Kbuf, V -> Vt (transposed)
  gemm_bt<2><<<dim3(32, 24), 256, 0, stream>>>(xb, WTall, bqkv, Qbuf, Kbuf, Vt, 4096, 3072, 2048);

  // 3. grouped flash attention -> Og [4096][2048] bf16
  attn_kernel<<<dim3(64, 8, 2), 256, 0, stream>>>(Qbuf, Kbuf, Vt, Og);

  // 4. output projection -> fp32 out
  gemm_bt<0><<<dim3(32, 16), 256, 0, stream>>>(Og, WoT, bo, out, nullptr, nullptr, 4096, 2048, 2048);
}

// Round 5
// 302.415 us; speedup vs baseline: 1.1225x; 1.0080x over previous
//
#include <hip/hip_runtime.h>
#include <hip/hip_bf16.h>

// GQA block: B=2, S=2048, HID=2048, H=32, G=8, D=64, QPG=4.
// bf16 MFMA 16x16x32; fp32 accumulate. m97-style staging:
// global_load_lds width=16 into unpadded LDS with XOR swizzle
// (chunk_phys = chunk_log ^ (row&7); rows of 64 shorts = 8 chunks of 16B).
// Fragment layouts (HW-verified, learn_hip m89/m120):
//   A-frag:  A[m=lane&15][k=quad*8+j]
//   B-frag:  B[k=quad*8+j][n=lane&15]
//   C/D:     col(n)=lane&15, row(m)=quad*4+reg
// Attention: S^T = K Q^T, O^T = V^T P^T (softmax axis on regs+quads).
// No-max softmax (scores ~N(0,0.9), exp2 has 2^30 headroom, shift-invariant).
// l on the MFMA pipe via register ones-fragment. GQA: block's 4 waves = the 4
// heads of one kv-group sharing one K/V LDS tile.
// R9:  in-register P (butterfly); conflicts 4.19M -> 0.
// R10: pure-VALU butterfly (cvt_pk_bf16 + permlane16_swap); attn 96 -> 81.5.
// R11: 64q + interleaved schedule FAILED correctness (spills @ ~272 VGPR demand
//      + permlane hazard blind spot in back-to-back inline asm).
// R12: 64q retry, de-risked: R7's proven phase-split schedule (one sc live at
//      a time, peak ~216 VGPR), s_nop hazard guards inside permlane asm,
//      expbfly dataflow byte-identical to R10. Rationale: per wave-iter the
//      16 ds_read_b128 (CU LDS pipe, the oversubscribed resource) feed 80
//      MFMAs at 4 qsets vs 40 at 2 — halves LDS traffic per FLOP.

typedef __attribute__((ext_vector_type(8))) short shortx8;
typedef __attribute__((ext_vector_type(4))) float floatx4;

#define SEQ 2048
#define QSC 0.1803368801111204f   // (1/8) * log2(e), folded into Wq/bq

#if __has_builtin(__builtin_amdgcn_exp2f)
#define EXP2F(x) __builtin_amdgcn_exp2f(x)
#else
#define EXP2F(x) __expf((x) * 0.6931471805599453f)
#endif

__device__ __forceinline__ unsigned short f2bf(float f) {      // RNE
  union { float f; unsigned u; } a; a.f = f;
  unsigned u = a.u;
  u += 0x7fffu + ((u >> 16) & 1u);
  return (unsigned short)(u >> 16);
}

// packed f32x2 -> bf16x2 (RNE), single instruction
__device__ __forceinline__ unsigned cvtpkbf(float lo, float hi) {
  unsigned r;
  asm("v_cvt_pk_bf16_f32 %0, %1, %2" : "=v"(r) : "v"(lo), "v"(hi));
  return r;
}

// v_permlane32_swap_b32: a = {a_lo32, b_lo32}, b = {a_hi32, b_hi32}
// s_nop guard: permlane cross-lane reads need producer wait states; the
// compiler's hazard recognizer can't see inside inline asm, so guard here.
__device__ __forceinline__ void plswap(unsigned &a, unsigned &b) {
  asm("s_nop 1\n\tv_permlane32_swap_b32 %0, %1" : "+v"(a), "+v"(b));
}
// v_permlane16_swap_b32: within each 32-half, a = {a_lo16, b_lo16}, b = {a_hi16, b_hi16}
__device__ __forceinline__ void pl16swap(unsigned &a, unsigned &b) {
  asm("s_nop 1\n\tv_permlane16_swap_b32 %0, %1" : "+v"(a), "+v"(b));
}

// async global->LDS, 16B per lane; LDS dst = uniform base + lane*16
__device__ __forceinline__ void gload16(const unsigned short* g, unsigned short* l) {
  __builtin_amdgcn_global_load_lds((const __attribute__((address_space(1))) void*)g,
                                   (__attribute__((address_space(3))) void*)l, 16, 0, 0);
}

// ---------------- prep: cast x, transpose+cast all weights, concat bias ----------
// grid (64,64,6), block (32,8). z: 0=Wq(*QSC) 1=Wk 2=Wv 3=Wo 4=cast-x 5=bias.
__global__ void prep_kernel(const float* __restrict__ x,
                            const float* __restrict__ Wq, const float* __restrict__ Wk,
                            const float* __restrict__ Wv, const float* __restrict__ Wo,
                            const float* __restrict__ bq, const float* __restrict__ bk,
                            const float* __restrict__ bv,
                            unsigned short* __restrict__ WT,
                            unsigned short* __restrict__ WoT,
                            unsigned short* __restrict__ xb,
                            float* __restrict__ bqkv) {
  const int z = blockIdx.z;
  if (z == 4) {                       // cast x -> bf16, 2048 floats per block
    int fb = blockIdx.y * 64 + blockIdx.x;
    int tid = threadIdx.y * 32 + threadIdx.x;
    int i = fb * 2048 + tid * 8;
    float4 v0 = *(const float4*)(x + i);
    float4 v1 = *(const float4*)(x + i + 4);
    ushort4 o0, o1;
    o0.x = f2bf(v0.x); o0.y = f2bf(v0.y); o0.z = f2bf(v0.z); o0.w = f2bf(v0.w);
    o1.x = f2bf(v1.x); o1.y = f2bf(v1.y); o1.z = f2bf(v1.z); o1.w = f2bf(v1.w);
    *(ushort4*)(xb + i) = o0;
    *(ushort4*)(xb + i + 4) = o1;
    return;
  }
  if (z == 5) {                       // concat bias
    int fb = blockIdx.y * 64 + blockIdx.x;
    if (fb >= 12) return;
    int i = fb * 256 + threadIdx.y * 32 + threadIdx.x;
    if (i < 2048) bqkv[i] = bq[i] * QSC;
    else if (i < 2560) bqkv[i] = bk[i - 2048];
    else if (i < 3072) bqkv[i] = bv[i - 2560];
    return;
  }
  const float* W; unsigned short* D; int N; float sc = 1.f;
  if (z == 0)      { W = Wq; D = WT;               N = 2048; sc = QSC; }
  else if (z == 1) { W = Wk; D = WT + 2048 * 2048; N = 512; }
  else if (z == 2) { W = Wv; D = WT + 2560 * 2048; N = 512; }
  else             { W = Wo; D = WoT;              N = 2048; }
  if (blockIdx.x * 32 >= N) return;

  __shared__ float tile[32][33];
  int xx = blockIdx.x * 32 + threadIdx.x;
  int y0 = blockIdx.y * 32;
  for (int i = 0; i < 32; i += 8)
    tile[threadIdx.y + i][threadIdx.x] = W[(size_t)(y0 + threadIdx.y + i) * N + xx];
  __syncthreads();
  int nx = y0 + threadIdx.x;
  int ny = blockIdx.x * 32 + threadIdx.y;
  for (int i = 0; i < 32; i += 8)
    D[(size_t)(ny + i) * 2048 + nx] = f2bf(tile[threadIdx.x][threadIdx.y + i] * sc);
}

// ---------------- bf16 GEMM (m97 structure): C = A @ BT^T + bias ----------------
// 128x128 tile, BK=64, 4 waves (2x2), global_load_lds staging, swizzled LDS.
// MODE 0: fp32 out. MODE 2: QKV split (Q -> Cout bf16, K -> Kbuf, V -> Vt[gb][d][s]).
template <int MODE>
__global__ __launch_bounds__(256) void gemm_bt(const unsigned short* __restrict__ A,
                                               const unsigned short* __restrict__ BT,
                                               const float* __restrict__ bias,
                                               void* __restrict__ Cout,
                                               unsigned short* __restrict__ Kbuf,
                                               unsigned short* __restrict__ Vt,
                                               int M, int N, int K) {
  __shared__ __align__(16) unsigned short As[128 * 64];
  __shared__ __align__(16) unsigned short Bs[128 * 64];
  const int m0 = blockIdx.x * 128, n0 = blockIdx.y * 128;
  const int tid = threadIdx.x;
  const int lane = tid & 63, wave = tid >> 6;
  const int l15 = lane & 15, quad = lane >> 4;
  const int wm = (wave & 1) * 64, wn = (wave >> 1) * 64;

  const int r8 = lane >> 3;
  const int clog = (lane & 7) ^ r8;
  const unsigned short* aSrc = A + (size_t)(m0 + wave * 32 + r8) * K + clog * 8;
  const unsigned short* bSrc = BT + (size_t)(n0 + wave * 32 + r8) * K + clog * 8;
  unsigned short* aDst = &As[wave * 2048];
  unsigned short* bDst = &Bs[wave * 2048];

  const int s = l15 & 7;
  int aoff[4], boff[4];
#pragma unroll
  for (int i = 0; i < 4; i++) aoff[i] = (wm + i * 16 + l15) * 64 + (quad ^ s) * 8;
#pragma unroll
  for (int j = 0; j < 4; j++) boff[j] = (wn + j * 16 + l15) * 64 + (quad ^ s) * 8;

  floatx4 acc[4][4];
#pragma unroll
  for (int i = 0; i < 4; i++)
#pragma unroll
    for (int j = 0; j < 4; j++)
#pragma unroll
      for (int r = 0; r < 4; r++) acc[i][j][r] = 0.f;

  for (int k0 = 0; k0 < K; k0 += 64) {
    __syncthreads();
#pragma unroll
    for (int j = 0; j < 4; j++) {
      gload16(aSrc + (size_t)j * 8 * K + k0, aDst + j * 512);
      gload16(bSrc + (size_t)j * 8 * K + k0, bDst + j * 512);
    }
    __syncthreads();
    {
      shortx8 af[4], bf[4];
#pragma unroll
      for (int i = 0; i < 4; i++) af[i] = *(const shortx8*)&As[aoff[i]];
#pragma unroll
      for (int j = 0; j < 4; j++) bf[j] = *(const shortx8*)&Bs[boff[j]];
#pragma unroll
      for (int i = 0; i < 4; i++)
#pragma unroll
        for (int j = 0; j < 4; j++)
          acc[i][j] = __builtin_amdgcn_mfma_f32_16x16x32_bf16(af[i], bf[j], acc[i][j], 0, 0, 0);
#pragma unroll
      for (int i = 0; i < 4; i++) af[i] = *(const shortx8*)&As[aoff[i] ^ 32];
#pragma unroll
      for (int j = 0; j < 4; j++) bf[j] = *(const shortx8*)&Bs[boff[j] ^ 32];
#pragma unroll
      for (int i = 0; i < 4; i++)
#pragma unroll
        for (int j = 0; j < 4; j++)
          acc[i][j] = __builtin_amdgcn_mfma_f32_16x16x32_bf16(af[i], bf[j], acc[i][j], 0, 0, 0);
    }
  }

#pragma unroll
  for (int i = 0; i < 4; i++) {
#pragma unroll
    for (int j = 0; j < 4; j++) {
      int col = n0 + wn + j * 16 + l15;
      float bv = bias[col];
#pragma unroll
      for (int r = 0; r < 4; r++) {
        int row = m0 + wm + i * 16 + quad * 4 + r;
        float v = acc[i][j][r] + bv;
        if (MODE == 0) {
          ((float*)Cout)[(size_t)row * N + col] = v;
        } else {
          if (col < 2048) {
            ((unsigned short*)Cout)[(size_t)row * 2048 + col] = f2bf(v);
          } else if (col < 2560) {
            Kbuf[(size_t)row * 512 + (col - 2048)] = f2bf(v);
          } else {
            int g = (col - 2560) >> 6, d = (col - 2560) & 63;
            int b = row >> 11, sidx = row & 2047;
            Vt[(size_t)(((g << 1) | b) * 64 + d) * 2048 + sidx] = f2bf(v);
          }
        }
      }
    }
  }
}

// ---------------- attention helpers (inlined; all static indexing) ---------------
__device__ __forceinline__ floatx4 mfma16(const shortx8 &a, const shortx8 &b, floatx4 c) {
  return __builtin_amdgcn_mfma_f32_16x16x32_bf16(a, b, c, 0, 0, 0);
}

__device__ __forceinline__ void qk8(const shortx8 (&kf)[4][2], const shortx8 (&qfa)[2],
                                    floatx4 (&sc)[4]) {
  __builtin_amdgcn_s_setprio(1);
#pragma unroll
  for (int i = 0; i < 4; i++) {
    floatx4 c = {0.f, 0.f, 0.f, 0.f};
    c = mfma16(kf[i][0], qfa[0], c);
    c = mfma16(kf[i][1], qfa[1], c);
    sc[i] = c;
  }
  __builtin_amdgcn_s_setprio(0);
}

// exp2 -> pack (cvt_pk) -> pure-VALU butterfly (R10-verified dataflow):
// E[i][c] = pair(t = 16i + 4quad + 2c) -> pf[ks].u32[m] = pair(t = 32ks+8quad+2m)
// via plswap (b5' = i&1) then pl16swap (src b4 = m>>1).
__device__ __forceinline__ void expbfly(const floatx4 (&sc)[4], shortx8 (&pf)[2]) {
  unsigned E00 = cvtpkbf(EXP2F(sc[0][0]), EXP2F(sc[0][1]));
  unsigned E01 = cvtpkbf(EXP2F(sc[0][2]), EXP2F(sc[0][3]));
  unsigned E10 = cvtpkbf(EXP2F(sc[1][0]), EXP2F(sc[1][1]));
  unsigned E11 = cvtpkbf(EXP2F(sc[1][2]), EXP2F(sc[1][3]));
  unsigned E20 = cvtpkbf(EXP2F(sc[2][0]), EXP2F(sc[2][1]));
  unsigned E21 = cvtpkbf(EXP2F(sc[2][2]), EXP2F(sc[2][3]));
  unsigned E30 = cvtpkbf(EXP2F(sc[3][0]), EXP2F(sc[3][1]));
  unsigned E31 = cvtpkbf(EXP2F(sc[3][2]), EXP2F(sc[3][3]));
  plswap(E00, E10); plswap(E01, E11);   // ks=0
  plswap(E20, E30); plswap(E21, E31);   // ks=1
  pl16swap(E00, E10); pl16swap(E01, E11);
  pl16swap(E20, E30); pl16swap(E21, E31);
  union { unsigned u[4]; shortx8 v; } P0, P1;
  P0.u[0] = E00; P0.u[1] = E01; P0.u[2] = E10; P0.u[3] = E11;
  P1.u[0] = E20; P1.u[1] = E21; P1.u[2] = E30; P1.u[3] = E31;
  pf[0] = P0.v;
  pf[1] = P1.v;
}

__device__ __forceinline__ void pv10(const shortx8 (&vf)[4][2], const shortx8 (&pf)[2],
                                     floatx4 (&oa)[4], floatx4 &la, const shortx8 &ones) {
#pragma unroll
  for (int ks = 0; ks < 2; ks++) {
    __builtin_amdgcn_s_setprio(1);
#pragma unroll
    for (int nd = 0; nd < 4; nd++)
      oa[nd] = mfma16(vf[nd][ks], pf[ks], oa[nd]);
    la = mfma16(ones, pf[ks], la);
    __builtin_amdgcn_s_setprio(0);
  }
}

// ---------------- flash attention (group-shared K/V, dbuf, in-register P) --------
// grid (S/64=32, G=8, B=2); wave w = head g*4+w. Each wave: 64 q rows as 4
// q-sets of 16 (R7-proven phase split). K/V dbuf (1 barrier/tile). P in
// registers (R10 butterfly). LDS 32 KB; launch_bounds(256,2) -> 256 VGPR.
__global__ __launch_bounds__(256, 2) void attn_kernel(const unsigned short* __restrict__ Qb,
                                                      const unsigned short* __restrict__ Kb,
                                                      const unsigned short* __restrict__ Vt,
                                                      unsigned short* __restrict__ O) {
  const int qt = blockIdx.x, g = blockIdx.y, b = blockIdx.z;
  const int tid = threadIdx.x;
  const int lane = tid & 63, wave = tid >> 6;
  const int h = g * 4 + wave;
  const int l15 = lane & 15, quad = lane >> 4;

  __shared__ __align__(16) unsigned short Ks[2][64 * 64];  // [t][d] swizzled, 2x8 KB
  __shared__ __align__(16) unsigned short Vs[2][64 * 64];  // [d][t] swizzled, 2x8 KB

  // Q fragments for 4 q-sets (64 q rows per wave)
  shortx8 qf[4][2];
  {
    const unsigned short* qp = Qb + (size_t)(b * SEQ + qt * 64 + l15) * 2048 + h * 64 + quad * 8;
#pragma unroll
    for (int a = 0; a < 4; a++) {
      qf[a][0] = *(const shortx8*)(qp + (size_t)a * 16 * 2048);
      qf[a][1] = *(const shortx8*)(qp + (size_t)a * 16 * 2048 + 32);
    }
  }

  // staging: wave stages rows wave*16..+15 of each tile (2 issues of 8 rows)
  const int r8 = lane >> 3;
  const int clog = (lane & 7) ^ r8;
  const unsigned short* kSrc = Kb + ((size_t)b * SEQ + wave * 16 + r8) * 512 + g * 64 + clog * 8;
  const unsigned short* vSrc = Vt + ((size_t)((g * 2 + b) * 64 + wave * 16 + r8)) * 2048 + clog * 8;

  const int s = l15 & 7;
  int foff[4];
#pragma unroll
  for (int i = 0; i < 4; i++) foff[i] = (i * 16 + l15) * 64 + ((quad ^ s) * 8);

  shortx8 ones;
#pragma unroll
  for (int j = 0; j < 8; j++) ones[j] = (short)0x3F80;     // bf16 1.0

  floatx4 oacc[4][4], lacc[4];
#pragma unroll
  for (int a = 0; a < 4; a++) {
#pragma unroll
    for (int r = 0; r < 4; r++) lacc[a][r] = 0.f;
#pragma unroll
    for (int nd = 0; nd < 4; nd++)
#pragma unroll
      for (int r = 0; r < 4; r++) oacc[a][nd][r] = 0.f;
  }

  // prologue: stage tile 0 into buffer 0
  {
    unsigned short* kD = &Ks[0][wave * 1024];
    unsigned short* vD = &Vs[0][wave * 1024];
    gload16(kSrc, kD);
    gload16(kSrc + (size_t)8 * 512, kD + 512);
    gload16(vSrc, vD);
    gload16(vSrc + (size_t)8 * 2048, vD + 512);
  }
  __syncthreads();

  for (int it = 0; it < SEQ / 64; it++) {
    const int p = it & 1;
    // prefetch next tile into the other buffer (async; drained by the
    // end-of-iter barrier, a full tile of compute later)
    if (it < SEQ / 64 - 1) {
      const size_t t1 = (size_t)(it + 1) * 64;
      unsigned short* kD = &Ks[p ^ 1][wave * 1024];
      unsigned short* vD = &Vs[p ^ 1][wave * 1024];
      gload16(kSrc + t1 * 512, kD);
      gload16(kSrc + (t1 + 8) * 512, kD + 512);
      gload16(vSrc + t1, vD);
      gload16(vSrc + (size_t)8 * 2048 + t1, vD + 512);
    }

    // K fragments (reused by all 4 q-sets)
    shortx8 kf[4][2];
#pragma unroll
    for (int i = 0; i < 4; i++) {
      kf[i][0] = *(const shortx8*)&Ks[p][foff[i]];
      kf[i][1] = *(const shortx8*)&Ks[p][foff[i] ^ 32];
    }

    // phase 1: per q-set QK^T -> exp -> butterfly -> pfr[a] (one sc live)
    shortx8 pfr[4][2];
#pragma unroll
    for (int a = 0; a < 4; a++) {
      floatx4 sc[4];
      qk8(kf, qf[a], sc);
      expbfly(sc, pfr[a]);
    }

    // phase 2: V fragments, then PV + l row-sum for all q-sets (MFMA burst)
    shortx8 vf[4][2];
#pragma unroll
    for (int nd = 0; nd < 4; nd++) {
      vf[nd][0] = *(const shortx8*)&Vs[p][foff[nd]];
      vf[nd][1] = *(const shortx8*)&Vs[p][foff[nd] ^ 32];
    }
#pragma unroll
    for (int a = 0; a < 4; a++)
      pv10(vf, pfr[a], oacc[a], lacc[a], ones);

    __syncthreads();   // buffer p free; prefetch into p^1 drained
  }

  // epilogue: lacc rows identical -> l = lacc[a][0]; O^T cols q, rows d contiguous
#pragma unroll
  for (int a = 0; a < 4; a++) {
    float inv = 1.f / lacc[a][0];
    unsigned short* oPtr = O + (size_t)(b * SEQ + qt * 64 + a * 16 + l15) * 2048 + h * 64 + quad * 4;
#pragma unroll
    for (int nd = 0; nd < 4; nd++) {
      uint2 w;
      w.x = (unsigned)f2bf(oacc[a][nd][0] * inv) | ((unsigned)f2bf(oacc[a][nd][1] * inv) << 16);
      w.y = (unsigned)f2bf(oacc[a][nd][2] * inv) | ((unsigned)f2bf(oacc[a][nd][3] * inv) << 16);
      *(uint2*)(oPtr + nd * 16) = w;
    }
  }
}

extern "C" void kernel_launch(void* const* d_in, const int* in_sizes, int n_in,
                              void* d_out, int out_size, void* d_ws, size_t ws_size,
                              hipStream_t stream) {
  const float* x  = (const float*)d_in[0];
  const float* Wq = (const float*)d_in[1];
  const float* bq = (const float*)d_in[2];
  const float* Wk = (const float*)d_in[3];
  const float* bk = (const float*)d_in[4];
  const float* Wv = (const float*)d_in[5];
  const float* bv = (const float*)d_in[6];
  const float* Wo = (const float*)d_in[7];
  const float* bo = (const float*)d_in[8];
  float* out = (float*)d_out;

  // workspace layout (62,930,944 B total)
  char* ws = (char*)d_ws;
  unsigned short* WTall = (unsigned short*)ws;                          // [3072][2048] 12,582,912
  unsigned short* WoT   = (unsigned short*)(ws + 12582912);             // [2048][2048]  8,388,608
  float*          bqkv  = (float*)(ws + 20971520);                      // [3072] + pad      16384
  unsigned short* xb    = (unsigned short*)(ws + 20987904);             // [4096][2048] 16,777,216
  unsigned short* Qbuf  = (unsigned short*)(ws + 37765120);             // [4096][2048] 16,777,216
  unsigned short* Kbuf  = (unsigned short*)(ws + 54542336);             // [4096][512]   4,194,304
  unsigned short* Vt    = (unsigned short*)(ws + 58736640);             // [16][64][2048] 4,194,304
  unsigned short* Og    = xb;  // attention output reuses xb

  // 1. prep: cast x, transpose+cast weights (Wq pre-scaled), concat bias
  prep_kernel<<<dim3(64, 64, 6), dim3(32, 8), 0, stream>>>(
      x, Wq, Wk, Wv, Wo, bq, bk, bv, WTall, WoT, xb, bqkv);

  // 2. QKV projection: Q -> Qbuf, K -> Kbuf, V -> Vt (transposed)
  gemm_bt<2><<<dim3(32, 24), 256, 0, stream>>>(xb, WTall, bqkv, Qbuf, Kbuf, Vt, 4096, 3072, 2048);

  // 3. grouped flash attention -> Og [4096][2048] bf16
  attn_kernel<<<dim3(32, 8, 2), 256, 0, stream>>>(Qbuf, Kbuf, Vt, Og);

  // 4. output projection -> fp32 out
  gemm_bt<0><<<dim3(32, 16), 256, 0, stream>>>(Og, WoT, bo, out, nullptr, nullptr, 4096, 2048, 2048);
}